// Round 8
// baseline (256.886 us; speedup 1.0000x reference)
//
#include <hip/hip_runtime.h>
#include <math.h>

#define CH 512
#define RED 64

typedef __attribute__((ext_vector_type(4))) float f32x4;
typedef long i64;

typedef const __attribute__((address_space(1))) void* gas_t;
typedef __attribute__((address_space(3))) void* las_t;

static __device__ __forceinline__ void gl16(const void* g, void* l) {
    __builtin_amdgcn_global_load_lds((gas_t)g, (las_t)l, 16, 0, 0);
}

// pack f32 -> fp8 e4m3
static __device__ __forceinline__ unsigned pk4(float a, float b, float c, float d) {
    int w = __builtin_amdgcn_cvt_pk_fp8_f32(a, b, 0, false);
    w = __builtin_amdgcn_cvt_pk_fp8_f32(c, d, w, true);
    return (unsigned)w;
}
static __device__ __forceinline__ unsigned char pk1(float a) {
    return (unsigned char)(__builtin_amdgcn_cvt_pk_fp8_f32(a, a, 0, false) & 0xFF);
}

// hardware exp2 (v_exp_f32 IS base-2)
static __device__ __forceinline__ float fexp2(float v) {
#if __has_builtin(__builtin_amdgcn_exp2f)
    return __builtin_amdgcn_exp2f(v);
#else
    float r; asm("v_exp_f32 %0, %1" : "=v"(r) : "v"(v)); return r;
#endif
}

// raw workgroup barrier with compiler memory fences (no implicit vmcnt(0) drain)
static __device__ __forceinline__ void barrier_raw() {
    asm volatile("" ::: "memory");
    __builtin_amdgcn_s_barrier();
    asm volatile("" ::: "memory");
}

// ---------------------------------------------------------------------------
// prep_w: Wq|Wk|Wv f32 -> Wcat fp8 [640][512]; rows 0-63 q, 64-127 k, 128-639 v.
// ---------------------------------------------------------------------------
__global__ __launch_bounds__(128) void prep_w(
    const float* __restrict__ Wq, const float* __restrict__ Wk,
    const float* __restrict__ Wv, unsigned char* __restrict__ Wcat)
{
    const int r = blockIdx.x, t = threadIdx.x;
    const float* src = (r < 64) ? (Wq + (size_t)r * CH)
                     : (r < 128) ? (Wk + (size_t)(r - 64) * CH)
                                 : (Wv + (size_t)(r - 128) * CH);
    const float4 v = *(const float4*)&src[t * 4];
    *(unsigned*)&Wcat[(size_t)r * CH + t * 4] = pk4(v.x, v.y, v.z, v.w);
}

// ---------------------------------------------------------------------------
// cast_xt: x f32 [b][c][n] -> xT fp8 [b][n][512].  64x64 tiles.
// ---------------------------------------------------------------------------
__global__ __launch_bounds__(256) void cast_xt(
    const float* __restrict__ x, unsigned char* __restrict__ xT, int n)
{
    __shared__ float sX[64][65];
    const int b = blockIdx.z, i0 = blockIdx.x * 64, c0 = blockIdx.y * 64;
    const int t = threadIdx.x;
    #pragma unroll
    for (int s = 0; s < 4; ++s) {
        const int id = s * 256 + t, c = id >> 4, seg = id & 15;
        *(float4*)&sX[c][seg * 4] = *(const float4*)&x[((size_t)b * CH + c0 + c) * n + i0 + seg * 4];
    }
    __syncthreads();
    const int i = t >> 2, cp = t & 3;
    uint4 w;
    w.x = pk4(sX[cp*16+ 0][i], sX[cp*16+ 1][i], sX[cp*16+ 2][i], sX[cp*16+ 3][i]);
    w.y = pk4(sX[cp*16+ 4][i], sX[cp*16+ 5][i], sX[cp*16+ 6][i], sX[cp*16+ 7][i]);
    w.z = pk4(sX[cp*16+ 8][i], sX[cp*16+ 9][i], sX[cp*16+10][i], sX[cp*16+11][i]);
    w.w = pk4(sX[cp*16+12][i], sX[cp*16+13][i], sX[cp*16+14][i], sX[cp*16+15][i]);
    *(uint4*)&xT[((size_t)b * n + i0 + i) * CH + c0 + cp * 16] = w;
}

// ---------------------------------------------------------------------------
// qkv_gemm v2 (fp8): out = xT * Wcat^T + bias.  128i x 128o tiles, K=512.
// Double-buffered staging with counted vmcnt.  q-rows scaled by log2(e).
// ---------------------------------------------------------------------------
__global__ __launch_bounds__(256, 4) void qkv_gemm(
    const unsigned char* __restrict__ xT, const unsigned char* __restrict__ Wcat,
    const float* __restrict__ bq, const float* __restrict__ bk,
    const float* __restrict__ bv,
    unsigned char* __restrict__ qF, unsigned char* __restrict__ kF,
    unsigned char* __restrict__ v2, int n)
{
    __shared__ char smem[40960];   // 2 x (sA 128x80 | sB 128x80)
    const int b = blockIdx.z, i0 = blockIdx.x * 128, o0 = blockIdx.y * 128;
    const int t = threadIdx.x, lane = t & 63;
    const int quad = lane >> 4, l16 = lane & 15;
    const int wrow = (t >> 6) & 1, wcol = t >> 7;

    f32x4 acc[4][4];
    const f32x4 zz = {0.f, 0.f, 0.f, 0.f};
    #pragma unroll
    for (int mi = 0; mi < 4; ++mi)
        #pragma unroll
        for (int ci = 0; ci < 4; ++ci) acc[mi][ci] = zz;

    const unsigned char* Ab = xT + ((size_t)b * n + i0) * CH;
    const unsigned char* Bb = Wcat + (size_t)o0 * CH;

    auto stageChunk = [&](int c0, char* dst) {
        #pragma unroll
        for (int s = 0; s < 5; ++s) {
            const int c = s * 256 + t;
            const bool isA = c < 640;
            const int tc = isA ? c : c - 640;
            const int r = tc / 5, p = (tc % 5) & 3;
            gl16((isA ? Ab : Bb) + (size_t)r * CH + c0 + p * 16,
                 dst + (isA ? 0 : 10240) + (size_t)tc * 16);
        }
    };

    stageChunk(0, smem);
    __syncthreads();                    // full drain once (chunk 0 ready)
    stageChunk(64, smem + 20480);       // chunk 1 in flight across chunk 0

    #pragma unroll
    for (int ci = 0; ci < 8; ++ci) {
        char* cb = smem + (ci & 1) * 20480;
        #pragma unroll
        for (int kk = 0; kk < 64; kk += 32) {
            i64 af[4], bf[4];
            #pragma unroll
            for (int mi = 0; mi < 4; ++mi)
                af[mi] = *(const i64*)(cb + (wrow * 64 + mi * 16 + l16) * 80 + kk + quad * 8);
            #pragma unroll
            for (int cj = 0; cj < 4; ++cj)
                bf[cj] = *(const i64*)(cb + 10240 + (wcol * 64 + cj * 16 + l16) * 80 + kk + quad * 8);
            __builtin_amdgcn_s_setprio(1);
            #pragma unroll
            for (int mi = 0; mi < 4; ++mi)
                #pragma unroll
                for (int cj = 0; cj < 4; ++cj)
                    acc[mi][cj] = __builtin_amdgcn_mfma_f32_16x16x32_fp8_fp8(af[mi], bf[cj], acc[mi][cj], 0, 0, 0);
            __builtin_amdgcn_s_setprio(0);
        }
        asm volatile("s_waitcnt lgkmcnt(0)" ::: "memory");
        barrier_raw();                  // all reads of cb done -> cb free
        if (ci + 2 < 8) {
            stageChunk((ci + 2) * 64, cb);
            asm volatile("s_waitcnt vmcnt(5)" ::: "memory");
            __builtin_amdgcn_sched_barrier(0);
            barrier_raw();
        } else if (ci + 1 < 8) {
            asm volatile("s_waitcnt vmcnt(0)" ::: "memory");
            __builtin_amdgcn_sched_barrier(0);
            barrier_raw();
        }
    }

    float bb[4], scl[4];
    #pragma unroll
    for (int ci = 0; ci < 4; ++ci) {
        const int o = wcol * 64 + ci * 16 + l16;
        if (o0 == 0) {
            bb[ci]  = (o < 64) ? bq[o] : bk[o - 64];
            scl[ci] = (o < 64) ? 1.44269504088896f : 1.0f;
        } else {
            bb[ci]  = bv[o0 - 128 + o];
            scl[ci] = 1.0f;
        }
    }
    __syncthreads();
    unsigned char* sE = (unsigned char*)smem;    // 128 x 144
    if (o0 == 0) {
        #pragma unroll
        for (int mi = 0; mi < 4; ++mi)
            #pragma unroll
            for (int ci = 0; ci < 4; ++ci)
                #pragma unroll
                for (int r = 0; r < 4; ++r)
                    sE[(wrow*64 + mi*16 + quad*4 + r) * 144 + wcol*64 + ci*16 + l16] =
                        pk1((acc[mi][ci][r] + bb[ci]) * scl[ci]);
    } else {
        #pragma unroll
        for (int mi = 0; mi < 4; ++mi)
            #pragma unroll
            for (int ci = 0; ci < 4; ++ci)
                #pragma unroll
                for (int r = 0; r < 4; ++r)
                    sE[(wcol*64 + ci*16 + l16) * 144 + wrow*64 + mi*16 + quad*4 + r] =
                        pk1(acc[mi][ci][r] + bb[ci]);
    }
    __syncthreads();
    if (o0 == 0) {
        #pragma unroll
        for (int u = 0; u < 2; ++u) {
            const int id = u * 256 + t, i = id >> 2, p = id & 3;
            *(uint4*)&qF[((size_t)b * n + i0 + i) * RED + p * 16] = *(const uint4*)&sE[i * 144 + p * 16];
        }
        #pragma unroll
        for (int u = 0; u < 2; ++u) {
            const int id = u * 256 + t, i = id >> 2, p = id & 3;
            *(uint4*)&kF[((size_t)b * n + i0 + i) * RED + p * 16] = *(const uint4*)&sE[i * 144 + 64 + p * 16];
        }
    } else {
        #pragma unroll
        for (int u = 0; u < 4; ++u) {
            const int id = u * 256 + t, o = id >> 3, p = id & 7;
            *(uint4*)&v2[((size_t)b * CH + (o0 - 128) + o) * n + i0 + p * 16] =
                *(const uint4*)&sE[o * 144 + p * 16];
        }
    }
}

// ---------------------------------------------------------------------------
// rowmax: m_i = max_j S' (bit-identical S' to attn's fp8 MFMA).
// ---------------------------------------------------------------------------
__global__ __launch_bounds__(256, 4) void rowmax(
    const unsigned char* __restrict__ qF, const unsigned char* __restrict__ kF,
    unsigned* __restrict__ mKey, int n)
{
    __shared__ char smem[20480];
    const int b = blockIdx.z, i0 = blockIdx.y * 128, j0 = blockIdx.x * 128;
    const int t = threadIdx.x, lane = t & 63;
    const int quad = lane >> 4, l16 = lane & 15;
    const int wrow = (t >> 6) & 1, wcol = t >> 7;

    const unsigned char* Qb = qF + ((size_t)b * n + i0) * RED;
    const unsigned char* Kb = kF + ((size_t)b * n + j0) * RED;
    #pragma unroll
    for (int s = 0; s < 5; ++s) {
        const int c = s * 256 + t;
        const bool isQ = c < 640;
        const int tc = isQ ? c : c - 640;
        const int r = tc / 5, p = (tc % 5) & 3;
        gl16((isQ ? Qb : Kb) + (size_t)r * RED + p * 16,
             smem + (isQ ? 0 : 10240) + (size_t)tc * 16);
    }
    __syncthreads();

    f32x4 acc[4][4];
    const f32x4 zz = {0.f, 0.f, 0.f, 0.f};
    #pragma unroll
    for (int mi = 0; mi < 4; ++mi)
        #pragma unroll
        for (int ci = 0; ci < 4; ++ci) acc[mi][ci] = zz;

    #pragma unroll
    for (int kk = 0; kk < 64; kk += 32) {
        i64 af[4], bf[4];
        #pragma unroll
        for (int mi = 0; mi < 4; ++mi)
            af[mi] = *(const i64*)(smem + (wrow * 64 + mi * 16 + l16) * 80 + kk + quad * 8);
        #pragma unroll
        for (int ci = 0; ci < 4; ++ci)
            bf[ci] = *(const i64*)(smem + 10240 + (wcol * 64 + ci * 16 + l16) * 80 + kk + quad * 8);
        #pragma unroll
        for (int mi = 0; mi < 4; ++mi)
            #pragma unroll
            for (int ci = 0; ci < 4; ++ci)
                acc[mi][ci] = __builtin_amdgcn_mfma_f32_16x16x32_fp8_fp8(af[mi], bf[ci], acc[mi][ci], 0, 0, 0);
    }

    #pragma unroll
    for (int mi = 0; mi < 4; ++mi)
        #pragma unroll
        for (int r = 0; r < 4; ++r) {
            float mx = fmaxf(fmaxf(acc[mi][0][r], acc[mi][1][r]),
                             fmaxf(acc[mi][2][r], acc[mi][3][r]));
            #pragma unroll
            for (int off = 1; off < 16; off <<= 1) mx = fmaxf(mx, __shfl_xor(mx, off));
            if (l16 == 0) {
                union { float f; unsigned u; } cv; cv.f = mx;
                const unsigned key = ((int)cv.u >= 0) ? (cv.u + 0x80000000u) : ~cv.u;
                atomicMax(&mKey[(size_t)b * n + i0 + wrow * 64 + mi * 16 + quad * 4 + r], key);
            }
        }
}

// ---------------------------------------------------------------------------
// attn v9: wave-autonomous softmax, 1 barrier/chunk.  Block = 64q x 256ch,
// 8 waves: wave (qt4=w&3, half=w>>2) owns q-tile qt4 (16q) x ch-half (128ch)
// and computes S for ALL 64 j itself (S redundancy 2x over halves).  P goes
// through a WAVE-PRIVATE 1KB LDS slice (write -> lgkm -> read back as
// B-operand; no s_barrier).  K/V triple-buffered (3x20KB): stage(c+2) issued
// at top of chunk c into the buffer freed at chunk c-1's barrier; one
// counted-vmcnt barrier per chunk.  lacc fully lane-local (il = 1/lacc after
// 2 shfls).  Per wave per chunk: 8 S-MFMA + 16 PV-MFMA, 64 barriers total.
// LDS 72KB -> 2 blocks/CU.  mrow precomputed (rowmax), exp2 domain.
// ---------------------------------------------------------------------------
#define BUF1  20480
#define BUF2  40960
#define PWOFF 61440
#define QOFF  69632

__global__ __launch_bounds__(512, 4) void attn(
    const unsigned char* __restrict__ qF,   // [b][n][64] fp8 (log2e-scaled)
    const unsigned char* __restrict__ kF,   // [b][n][64] fp8
    const unsigned char* __restrict__ v2,   // [b][512][n] fp8
    const unsigned* __restrict__ mKey,
    const float* __restrict__ x, const float* __restrict__ gamma,
    float* __restrict__ y, int n)
{
    __shared__ char smem[73728];
    const int b = blockIdx.x >> 1, ch0 = (blockIdx.x & 1) * 256;
    const int i0 = blockIdx.y * 64;
    const int t = threadIdx.x, lane = t & 63, w = t >> 6;
    const int quad = lane >> 4, l16 = lane & 15;
    const int qt4 = w & 3, half = w >> 2;
    const int sw = (l16 >> 1) & 3;          // staging swizzle key (row-derived)
    const int boff = (quad & 1) * 8;
    const int phalf = quad >> 1;
    const int p0 = phalf ^ sw;              // kki=0 part; kki=1 = addr ^ 32
    const int pX = (l16 & 7) << 3;          // P-private swizzle (bits 3..5)

    // per-lane invariant LDS byte offsets
    const int kfA = l16 * 64 + p0 * 16 + boff;                        // + cur + jt*1024
    const int vA  = 4096 + (half * 128 + l16) * 64 + p0 * 16 + boff;  // + cur + cht*1024
    const int qA  = QOFF + (qt4 * 16 + l16) * 64 + p0 * 16 + boff;
    const int pwB = PWOFF + w * 1024 + l16 * 64;                      // + ((jt*16+quad*4)^pX)
    const int prA0 = pwB + ((quad * 8) ^ pX);                         // PV B-frag kki=0
    const int prA1 = pwB + ((32 + quad * 8) ^ pX);                    // PV B-frag kki=1

    const unsigned char* Qb = qF + ((size_t)b * n + i0) * RED;
    const unsigned char* Kb = kF + (size_t)b * n * RED;
    const unsigned char* Vb = v2 + ((size_t)b * CH + ch0) * n;

    // staging geometry (source carries the XOR swizzle; dst linear) — proven
    const int r = t >> 2, s4 = t & 3, gs = s4 ^ ((r >> 1) & 3);
    const int kDst = t * 16, vDst0 = 4096 + t * 16, vDst1 = 12288 + t * 16;
    const size_t vHalf = (size_t)128 * n;
    const unsigned char* kSrc0 = Kb + (size_t)r * RED + gs * 16;
    const unsigned char* vSrc0 = Vb + (size_t)r * n + gs * 16;

    // ---- prologue: Q + chunk 0 (full drain once)
    if (t < 256) {
        gl16(Qb + (size_t)r * RED + gs * 16, smem + QOFF + kDst);
        gl16(kSrc0, smem + kDst);
    }
    gl16(vSrc0, smem + vDst0);
    gl16(vSrc0 + vHalf, smem + vDst1);

    float mrow;
    {
        const unsigned u = mKey[(size_t)b * n + i0 + qt4 * 16 + l16];
        const unsigned bits = (u >= 0x80000000u) ? (u - 0x80000000u) : ~u;
        union { unsigned u; float f; } cv; cv.u = bits;
        mrow = cv.f;
    }
    __syncthreads();   // Q + chunk0 landed; vmcnt now 0 on all waves

    // ---- Q fragments (Q region never reused -> no barrier needed after)
    i64 qreg[2];
    qreg[0] = *(const i64*)(smem + qA);
    qreg[1] = *(const i64*)(smem + (qA ^ 32));

    const int nchunks = n >> 6;
    if (nchunks > 1) {   // chunk 1 in flight across chunk 0
        if (t < 256) gl16(kSrc0 + 4096, smem + BUF1 + kDst);
        gl16(vSrc0 + 64, smem + BUF1 + vDst0);
        gl16(vSrc0 + vHalf + 64, smem + BUF1 + vDst1);
    }
    const unsigned char* kP  = kSrc0 + 8192;
    const unsigned char* vP0 = vSrc0 + 128;
    const unsigned char* vP1 = vSrc0 + vHalf + 128;

    f32x4 acc[8];
    const f32x4 zz = {0.f, 0.f, 0.f, 0.f};
    #pragma unroll
    for (int cht = 0; cht < 8; ++cht) acc[cht] = zz;
    float lacc = 0.f;

    int cur = 0, nx1 = BUF1, nx2 = BUF2;

    for (int c = 0; c < nchunks; ++c) {
        // ---- stage chunk c+2 into the buffer freed at chunk c-1's barrier
        if (c + 2 < nchunks) {
            if (t < 256) gl16(kP, smem + nx2 + kDst);
            gl16(vP0, smem + nx2 + vDst0);
            gl16(vP1, smem + nx2 + vDst1);
            kP += 4096; vP0 += 64; vP1 += 64;
        }

        // ---- S: all 64 j for this wave's 16 q (4 j-tiles x kki 2)
        f32x4 S[4];
        S[0] = zz; S[1] = zz; S[2] = zz; S[3] = zz;
        __builtin_amdgcn_s_setprio(1);
        #pragma unroll
        for (int jt = 0; jt < 4; ++jt) {
            const i64 kf0 = *(const i64*)(smem + cur + kfA + jt * 1024);
            const i64 kf1 = *(const i64*)(smem + cur + (kfA ^ 32) + jt * 1024);
            S[jt] = __builtin_amdgcn_mfma_f32_16x16x32_fp8_fp8(kf0, qreg[0], S[jt], 0, 0, 0);
            S[jt] = __builtin_amdgcn_mfma_f32_16x16x32_fp8_fp8(kf1, qreg[1], S[jt], 0, 0, 0);
        }
        __builtin_amdgcn_s_setprio(0);

        // ---- softmax + wave-private P write (no cross-wave traffic)
        #pragma unroll
        for (int jt = 0; jt < 4; ++jt) {
            const float e0 = fexp2(S[jt][0] - mrow);
            const float e1 = fexp2(S[jt][1] - mrow);
            const float e2 = fexp2(S[jt][2] - mrow);
            const float e3 = fexp2(S[jt][3] - mrow);
            lacc += (e0 + e1) + (e2 + e3);
            *(unsigned*)(smem + pwB + ((jt * 16 + quad * 4) ^ pX)) = pk4(e0, e1, e2, e3);
        }
        asm volatile("s_waitcnt lgkmcnt(0)" ::: "memory");
        __builtin_amdgcn_sched_barrier(0);   // rule #18: fence reads below

        const i64 pb0 = *(const i64*)(smem + prA0);
        const i64 pb1 = *(const i64*)(smem + prA1);

        // ---- PV: 8 ch-tiles x kki 2 (16 MFMA, 8 independent acc chains)
        __builtin_amdgcn_s_setprio(1);
        #pragma unroll
        for (int cht = 0; cht < 8; ++cht) {
            const i64 vf0 = *(const i64*)(smem + cur + vA + cht * 1024);
            acc[cht] = __builtin_amdgcn_mfma_f32_16x16x32_fp8_fp8(vf0, pb0, acc[cht], 0, 0, 0);
        }
        #pragma unroll
        for (int cht = 0; cht < 8; ++cht) {
            const i64 vf1 = *(const i64*)(smem + cur + (vA ^ 32) + cht * 1024);
            acc[cht] = __builtin_amdgcn_mfma_f32_16x16x32_fp8_fp8(vf1, pb1, acc[cht], 0, 0, 0);
        }
        __builtin_amdgcn_s_setprio(0);

        // ---- one barrier per chunk: counted vmcnt (chunk c+1 landed)
        if (c + 2 < nchunks) {
            if (w < 4) asm volatile("s_waitcnt vmcnt(3)" ::: "memory");
            else       asm volatile("s_waitcnt vmcnt(2)" ::: "memory");
            __builtin_amdgcn_sched_barrier(0);
            barrier_raw();
        } else if (c + 1 < nchunks) {
            asm volatile("s_waitcnt vmcnt(0)" ::: "memory");
            __builtin_amdgcn_sched_barrier(0);
            barrier_raw();
        }
        const int tmp = cur; cur = nx1; nx1 = nx2; nx2 = tmp;
    }

    // ---- lane-local l: sum over quads (both halves computed identical lacc)
    lacc += __shfl_xor(lacc, 16);
    lacc += __shfl_xor(lacc, 32);
    const float il = 1.0f / lacc;

    // ---- epilogue: 4 rounds of 64 channels; transpose via LDS, y = g*(O/l)+x
    const float gm = gamma[0];
    float* sT = (float*)smem;   // [64][68] f32 = 17.4 KB (aliases buf0)
    #pragma unroll
    for (int cr = 0; cr < 4; ++cr) {
        __syncthreads();
        if (half == (cr >> 1)) {
            #pragma unroll
            for (int k = 0; k < 4; ++k)
                #pragma unroll
                for (int rr = 0; rr < 4; ++rr)
                    sT[(k * 16 + quad * 4 + rr) * 68 + qt4 * 16 + l16] =
                        acc[(cr & 1) * 4 + k][rr] * il;
        }
        __syncthreads();
        const int row = t >> 3, seg = (t & 7) * 8;
        const size_t gb = ((size_t)b * CH + ch0 + cr * 64 + row) * n + i0 + seg;
        #pragma unroll
        for (int u = 0; u < 2; ++u) {
            const float4 xv = *(const float4*)&x[gb + u * 4];
            const float* op = &sT[row * 68 + seg + u * 4];
            float4 yv;
            yv.x = gm * op[0] + xv.x;
            yv.y = gm * op[1] + xv.y;
            yv.z = gm * op[2] + xv.z;
            yv.w = gm * op[3] + xv.w;
            *(float4*)&y[gb + u * 4] = yv;
        }
    }
}

// ---------------------------------------------------------------------------
extern "C" void kernel_launch(void* const* d_in, const int* in_sizes, int n_in,
                              void* d_out, int out_size, void* d_ws, size_t ws_size,
                              hipStream_t stream) {
    const float* x     = (const float*)d_in[0];
    const float* Wq    = (const float*)d_in[1];
    const float* bq    = (const float*)d_in[2];
    const float* Wk    = (const float*)d_in[3];
    const float* bk    = (const float*)d_in[4];
    const float* Wv    = (const float*)d_in[5];
    const float* bv    = (const float*)d_in[6];
    const float* gamma = (const float*)d_in[7];
    float* y = (float*)d_out;

    const int N = 64 * 64;
    const int B = in_sizes[0] / (CH * N);   // = 4

    char* ws = (char*)d_ws;
    unsigned char* xT   = (unsigned char*)ws;  ws += (size_t)B * N * CH;
    unsigned char* qF   = (unsigned char*)ws;  ws += (size_t)B * N * RED;
    unsigned char* kF   = (unsigned char*)ws;  ws += (size_t)B * N * RED;
    unsigned char* v2   = (unsigned char*)ws;  ws += (size_t)B * CH * N;
    unsigned char* Wcat = (unsigned char*)ws;  ws += (size_t)640 * CH;
    unsigned* mKey      = (unsigned*)ws;

    hipMemsetAsync(mKey, 0, (size_t)B * N * 4, stream);

    prep_w<<<dim3(640), 128, 0, stream>>>(Wq, Wk, Wv, Wcat);
    cast_xt<<<dim3(N / 64, CH / 64, B), 256, 0, stream>>>(x, xT, N);
    qkv_gemm<<<dim3(N / 128, 5, B), 256, 0, stream>>>(xT, Wcat, bq, bk, bv, qF, kF, v2, N);
    rowmax<<<dim3(N / 128, N / 128, B), 256, 0, stream>>>(qF, kF, mKey, N);
    attn<<<dim3(2 * B, N / 64), 512, 0, stream>>>(qF, kF, v2, mKey, x, gamma, y, N);
}